// Round 6
// baseline (125.517 us; speedup 1.0000x reference)
//
#include <hip/hip_runtime.h>
#include <hip/hip_bf16.h>

#define B_SZ 16384
#define E_SZ 128
#define H_SZ 256
#define A_SZ 20
#define K_SZ 384           // H + E
#define BH   (B_SZ * H_SZ) // 4194304

typedef __attribute__((ext_vector_type(8))) short  short8v;
typedef __attribute__((ext_vector_type(4))) float  f32x4;
typedef __attribute__((ext_vector_type(2))) float  f32x2;
typedef __attribute__((ext_vector_type(4))) unsigned short ushort4v;
typedef __attribute__((ext_vector_type(2))) unsigned short ushort2v;

__device__ __forceinline__ unsigned short f2bf(float f) {
    union { float f; unsigned u; } v; v.f = f;
    unsigned r = v.u + 0x7fffu + ((v.u >> 16) & 1u);   // RNE
    return (unsigned short)(r >> 16);
}

__device__ __forceinline__ float wsum(float v) {
    #pragma unroll
    for (int off = 32; off > 0; off >>= 1) v += __shfl_xor(v, off, 64);
    return v;
}

__device__ __forceinline__ float sigm(float x) { return 1.0f / (1.0f + __expf(-x)); }

struct Ptr8 { const float* p[8]; };

// ---------------- Kernel 1: attention + bf16 pack: Hb=[h], A1x=[x1], A2x=[x2m]
__global__ __launch_bounds__(256) void attn_pack(
    const float* __restrict__ x1, const float* __restrict__ x2,
    const float* __restrict__ h,  const float* __restrict__ wa,
    unsigned short* __restrict__ Hb, unsigned short* __restrict__ A1x,
    unsigned short* __restrict__ A2x)
{
    const int row  = blockIdx.x * 4 + (threadIdx.x >> 6);
    const int lane = threadIdx.x & 63;

    const f32x4 hv   = *(const f32x4*)(h  + (size_t)row * H_SZ + 4 * lane);
    const f32x2 x1v  = *(const f32x2*)(x1 + (size_t)row * E_SZ + 2 * lane);
    const f32x4 wah  = *(const f32x4*)(wa + 4 * lane);
    const f32x2 wax1 = *(const f32x2*)(wa + H_SZ + 2 * lane);
    const f32x2 wax2 = *(const f32x2*)(wa + H_SZ + E_SZ + 2 * lane);

    float base = hv.x * wah.x + hv.y * wah.y + hv.z * wah.z + hv.w * wah.w
               + x1v.x * wax1.x + x1v.y * wax1.y;

    f32x2 xv[A_SZ];
    float sp[A_SZ];
    const float* x2r = x2 + (size_t)row * A_SZ * E_SZ;
    #pragma unroll
    for (int a = 0; a < A_SZ; ++a) {
        xv[a] = *(const f32x2*)(x2r + a * E_SZ + 2 * lane);
        sp[a] = xv[a].x * wax2.x + xv[a].y * wax2.y;
    }

    base = wsum(base);
    #pragma unroll
    for (int a = 0; a < A_SZ; ++a) sp[a] = wsum(sp[a]) + base;

    float mx = sp[0];
    #pragma unroll
    for (int a = 1; a < A_SZ; ++a) mx = fmaxf(mx, sp[a]);
    float s = 0.0f;
    #pragma unroll
    for (int a = 0; a < A_SZ; ++a) { sp[a] = __expf(sp[a] - mx); s += sp[a]; }
    const float inv = 1.0f / s;

    float m0 = 0.0f, m1 = 0.0f;
    #pragma unroll
    for (int a = 0; a < A_SZ; ++a) { m0 += sp[a] * xv[a].x; m1 += sp[a] * xv[a].y; }
    m0 *= inv; m1 *= inv;

    ushort4v hb;
    hb.x = f2bf(hv.x); hb.y = f2bf(hv.y); hb.z = f2bf(hv.z); hb.w = f2bf(hv.w);
    *(ushort4v*)(Hb + (size_t)row * H_SZ + 4 * lane) = hb;
    ushort2v x1b; x1b.x = f2bf(x1v.x); x1b.y = f2bf(x1v.y);
    *(ushort2v*)(A1x + (size_t)row * E_SZ + 2 * lane) = x1b;
    ushort2v mb; mb.x = f2bf(m0); mb.y = f2bf(m1);
    *(ushort2v*)(A2x + (size_t)row * E_SZ + 2 * lane) = mb;
}

// ---------------- Kernel 2: weight pack: Wt[nn][k], nn = hcblk*256+g*32+hcin
__global__ __launch_bounds__(256) void pack_w(Ptr8 ws, unsigned short* __restrict__ Wt)
{
    const int g = blockIdx.z, nt = blockIdx.y, kt = blockIdx.x;
    __shared__ float tile[64][65];
    const float* W = ws.p[g];
    const int c = threadIdx.x & 63, r0 = threadIdx.x >> 6;
    #pragma unroll
    for (int i = 0; i < 16; ++i) {
        int r = r0 + 4 * i;
        tile[r][c] = W[(size_t)(kt * 64 + r) * H_SZ + nt * 64 + c];
    }
    __syncthreads();
    #pragma unroll
    for (int i = 0; i < 16; ++i) {
        int rr = r0 + 4 * i;
        const int hcol = nt * 64 + rr;
        const int nn = ((hcol >> 5) << 8) + g * 32 + (hcol & 31);
        Wt[(size_t)nn * K_SZ + kt * 64 + c] = f2bf(tile[c][rr]);
    }
}

// ---------------- Kernel 3: GEMM + fused LSTM epilogue, single-buf 64KB -----
// Grid 1024 x 512thr, 2 blocks/CU. Block = 128 rows x 256 cols (8g x 32hc).
// 8 waves 2Mx4N, wave tile 64x64. A shared for K<256 (h part), split after.
__global__ __launch_bounds__(512, 4) void gemm_ep(
    const unsigned short* __restrict__ Hb, const unsigned short* __restrict__ A1x,
    const unsigned short* __restrict__ A2x, const unsigned short* __restrict__ Wt,
    Ptr8 bias, const float* __restrict__ c1, const float* __restrict__ c2,
    float* __restrict__ out)
{
    __shared__ char smem[65536];   // A 0..32K (16K used for ks<4) | B 32K..64K
    const int tid = threadIdx.x, w = tid >> 6, lane = tid & 63;
    const int d = blockIdx.x;
    // XCD-aware (bijective for 1024 = 8*128): XCD owns 16 contiguous rbs.
    const int rb  = (d & 7) * 16 + (d >> 6);
    const int hcb = (d >> 3) & 7;
    const int row0 = rb * 128, hcol0 = hcb * 32;
    const int fr = lane & 15, hi = lane >> 4;
    const int wM = w >> 2, wN = w & 3;

    const unsigned short* Bpan = Wt + (size_t)hcb * 256 * K_SZ;
    const int lr = lane >> 3, sl = lane & 7;   // 8 rows x 8 16B-slots per glds

    // ---- prefetch ALL epilogue operands before K-loop (latency hidden) ----
    const int hcin = tid & 31, rgrp = tid >> 5;     // rgrp 0..15
    float c1p[2][4], c2p[2][4], bia[8];
    #pragma unroll
    for (int p = 0; p < 2; ++p)
        #pragma unroll
        for (int rr = 0; rr < 4; ++rr) {
            const int R = p * 64 + rgrp * 4 + rr;
            c1p[p][rr] = c1[(size_t)(row0 + R) * H_SZ + hcol0 + hcin];
            c2p[p][rr] = c2[(size_t)(row0 + R) * H_SZ + hcol0 + hcin];
        }
    #pragma unroll
    for (int g = 0; g < 8; ++g) bia[g] = bias.p[g][hcol0 + hcin];

    auto glds = [&](const unsigned short* src, int dstoff) {
        __builtin_amdgcn_global_load_lds(
            (const __attribute__((address_space(1))) unsigned int*)src,
            (__attribute__((address_space(3))) unsigned int*)(smem + dstoff), 16, 0, 0);
    };
    auto stage = [&](int ks) {
        #pragma unroll
        for (int j = 0; j < 4; ++j) {            // B panel: 256 cols x 64 k
            const int C = j * 64 + w * 8 + lr;
            glds(Bpan + (size_t)C * K_SZ + ks * 64 + ((sl ^ (C & 7)) << 3),
                 32768 + j * 8192 + w * 1024);
        }
        if (ks < 4) {                            // shared h panel
            #pragma unroll
            for (int i = 0; i < 2; ++i) {
                const int R = i * 64 + w * 8 + lr;
                glds(Hb + (size_t)(row0 + R) * H_SZ + ks * 64 + ((sl ^ (R & 7)) << 3),
                     i * 8192 + w * 1024);
            }
        } else {                                 // split x panels
            const int ko = (ks - 4) * 64;
            #pragma unroll
            for (int i = 0; i < 2; ++i) {
                const int R = i * 64 + w * 8 + lr;
                const int sw = (sl ^ (R & 7)) << 3;
                glds(A1x + (size_t)(row0 + R) * E_SZ + ko + sw,         i * 8192 + w * 1024);
                glds(A2x + (size_t)(row0 + R) * E_SZ + ko + sw, 16384 + i * 8192 + w * 1024);
            }
        }
    };

    f32x4 acc[4][4];
    #pragma unroll
    for (int mi = 0; mi < 4; ++mi)
        #pragma unroll
        for (int ni = 0; ni < 4; ++ni) acc[mi][ni] = (f32x4){0.f, 0.f, 0.f, 0.f};

    stage(0);
    for (int ks = 0; ks < 6; ++ks) {
        __syncthreads();                         // staging of ks complete
        const int apo = (ks >= 4 && wN >= 2) ? 16384 : 0;
        #pragma unroll
        for (int kk = 0; kk < 2; ++kk) {
            short8v af[4], bf[4];
            #pragma unroll
            for (int mi = 0; mi < 4; ++mi) {
                const int R = wM * 64 + mi * 16 + fr;
                af[mi] = *(const short8v*)(smem + apo + R * 128 +
                                           ((((kk << 2) + hi) ^ (R & 7)) << 4));
            }
            #pragma unroll
            for (int ni = 0; ni < 4; ++ni) {
                const int C = wN * 64 + ni * 16 + fr;
                bf[ni] = *(const short8v*)(smem + 32768 + C * 128 +
                                           ((((kk << 2) + hi) ^ (C & 7)) << 4));
            }
            #pragma unroll
            for (int mi = 0; mi < 4; ++mi)
                #pragma unroll
                for (int ni = 0; ni < 4; ++ni)
                    acc[mi][ni] = __builtin_amdgcn_mfma_f32_16x16x32_bf16(
                        af[mi], bf[ni], acc[mi][ni], 0, 0, 0);
        }
        __syncthreads();                         // all reads done
        if (ks < 5) stage(ks + 1);               // refill (other block overlaps)
    }

    // ---- epilogue: two 64-row phases through the 64KB buffer ----
    float* gf = (float*)smem;                    // [8 g][64 r][32 c], parity-rot
    #pragma unroll
    for (int p = 0; p < 2; ++p) {
        __syncthreads();
        if (wM == p) {
            #pragma unroll
            for (int mi = 0; mi < 4; ++mi)
                #pragma unroll
                for (int ni = 0; ni < 4; ++ni)
                    #pragma unroll
                    for (int j = 0; j < 4; ++j) {
                        const int Rl2 = mi * 16 + hi * 4 + j;          // 0..63
                        const int g   = wN * 2 + (ni >> 1);
                        const int hc  = (ni & 1) * 16 + fr;
                        const int hcr = (hc + (((Rl2 >> 2) & 1) << 4)) & 31;
                        gf[(g * 64 + Rl2) * 32 + hcr] = acc[mi][ni][j];
                    }
        }
        __syncthreads();
        #pragma unroll
        for (int rr = 0; rr < 4; ++rr) {
            const int Rl2 = rgrp * 4 + rr;
            const int hcr = (hcin + (((Rl2 >> 2) & 1) << 4)) & 31;
            float G[8];
            #pragma unroll
            for (int g = 0; g < 8; ++g) G[g] = gf[(g * 64 + Rl2) * 32 + hcr] + bia[g];

            const float f1  = sigm(G[0]);
            const float i1  = sigm(G[1]);
            const float c1t = tanhf(G[2]);
            const float o1  = G[3];
            const float f2  = sigm(G[4]);
            const float i2  = sigm(G[5]);
            const float c2t = tanhf(G[6]);
            const float o2  = G[7];
            const float c1n = f1 * c1p[p][rr] + i1 * c1t;
            const float c2n = f2 * c2p[p][rr] + i2 * c2t;
            const float mo  = fmaxf(o1, o2);
            const float e1  = __expf(o1 - mo), e2 = __expf(o2 - mo);
            const float g0  = e1 / (e1 + e2);
            const float hn  = g0 * tanhf(c1n) + (1.0f - g0) * tanhf(c2n);

            const size_t o0 = (size_t)(row0 + p * 64 + Rl2) * H_SZ + hcol0 + hcin;
            out[o0]          = hn;
            out[BH + o0]     = c1n;
            out[2 * BH + o0] = c2n;
        }
    }
}

// ---------------- host ----------------
extern "C" void kernel_launch(void* const* d_in, const int* in_sizes, int n_in,
                              void* d_out, int out_size, void* d_ws, size_t ws_size,
                              hipStream_t stream)
{
    const float* x1 = (const float*)d_in[0];
    const float* x2 = (const float*)d_in[1];
    const float* h  = (const float*)d_in[2];
    const float* c1 = (const float*)d_in[3];
    const float* c2 = (const float*)d_in[4];
    const float* wa = (const float*)d_in[21];

    // gate order: 0..3 = cell1 {f,i,c,o}; 4..7 = cell2 {f,i,c,o}
    Ptr8 wptr, bptr;
    wptr.p[0] = (const float*)d_in[5];  wptr.p[1] = (const float*)d_in[9];
    wptr.p[2] = (const float*)d_in[13]; wptr.p[3] = (const float*)d_in[17];
    wptr.p[4] = (const float*)d_in[6];  wptr.p[5] = (const float*)d_in[10];
    wptr.p[6] = (const float*)d_in[14]; wptr.p[7] = (const float*)d_in[18];
    bptr.p[0] = (const float*)d_in[7];  bptr.p[1] = (const float*)d_in[11];
    bptr.p[2] = (const float*)d_in[15]; bptr.p[3] = (const float*)d_in[19];
    bptr.p[4] = (const float*)d_in[8];  bptr.p[5] = (const float*)d_in[12];
    bptr.p[6] = (const float*)d_in[16]; bptr.p[7] = (const float*)d_in[20];

    char* ws = (char*)d_ws;
    unsigned short* Hb  = (unsigned short*)(ws);              // 8.4 MB
    unsigned short* A1x = (unsigned short*)(ws + 8388608);    // 4.2 MB
    unsigned short* A2x = (unsigned short*)(ws + 12582912);   // 4.2 MB
    unsigned short* Wt  = (unsigned short*)(ws + 16777216);   // 1.6 MB

    pack_w<<<dim3(6, 4, 8), 256, 0, stream>>>(wptr, Wt);
    attn_pack<<<B_SZ / 4, 256, 0, stream>>>(x1, x2, h, wa, Hb, A1x, A2x);
    gemm_ep<<<1024, 512, 0, stream>>>(Hb, A1x, A2x, Wt, bptr, c1, c2, (float*)d_out);
}

// Round 7
// 114.640 us; speedup vs baseline: 1.0949x; 1.0949x over previous
//
#include <hip/hip_runtime.h>
#include <hip/hip_bf16.h>

#define B_SZ 16384
#define E_SZ 128
#define H_SZ 256
#define A_SZ 20
#define K_SZ 384           // H + E
#define BH   (B_SZ * H_SZ) // 4194304

typedef __attribute__((ext_vector_type(8))) short  short8v;
typedef __attribute__((ext_vector_type(4))) float  f32x4;
typedef __attribute__((ext_vector_type(2))) float  f32x2;
typedef __attribute__((ext_vector_type(4))) unsigned short ushort4v;
typedef __attribute__((ext_vector_type(2))) unsigned short ushort2v;

__device__ __forceinline__ unsigned short f2bf(float f) {
    union { float f; unsigned u; } v; v.f = f;
    unsigned r = v.u + 0x7fffu + ((v.u >> 16) & 1u);   // RNE
    return (unsigned short)(r >> 16);
}

__device__ __forceinline__ float wsum(float v) {
    #pragma unroll
    for (int off = 32; off > 0; off >>= 1) v += __shfl_xor(v, off, 64);
    return v;
}

__device__ __forceinline__ float sigm(float x) { return 1.0f / (1.0f + __expf(-x)); }

struct Ptr8 { const float* p[8]; };

// ---------------- Kernel 1: attention + bf16 pack: Hb=[h], A1x=[x1], A2x=[x2m]
__global__ __launch_bounds__(256) void attn_pack(
    const float* __restrict__ x1, const float* __restrict__ x2,
    const float* __restrict__ h,  const float* __restrict__ wa,
    unsigned short* __restrict__ Hb, unsigned short* __restrict__ A1x,
    unsigned short* __restrict__ A2x)
{
    const int row  = blockIdx.x * 4 + (threadIdx.x >> 6);
    const int lane = threadIdx.x & 63;

    const f32x4 hv   = *(const f32x4*)(h  + (size_t)row * H_SZ + 4 * lane);
    const f32x2 x1v  = *(const f32x2*)(x1 + (size_t)row * E_SZ + 2 * lane);
    const f32x4 wah  = *(const f32x4*)(wa + 4 * lane);
    const f32x2 wax1 = *(const f32x2*)(wa + H_SZ + 2 * lane);
    const f32x2 wax2 = *(const f32x2*)(wa + H_SZ + E_SZ + 2 * lane);

    float base = hv.x * wah.x + hv.y * wah.y + hv.z * wah.z + hv.w * wah.w
               + x1v.x * wax1.x + x1v.y * wax1.y;

    f32x2 xv[A_SZ];
    float sp[A_SZ];
    const float* x2r = x2 + (size_t)row * A_SZ * E_SZ;
    #pragma unroll
    for (int a = 0; a < A_SZ; ++a) {
        xv[a] = *(const f32x2*)(x2r + a * E_SZ + 2 * lane);
        sp[a] = xv[a].x * wax2.x + xv[a].y * wax2.y;
    }

    base = wsum(base);
    #pragma unroll
    for (int a = 0; a < A_SZ; ++a) sp[a] = wsum(sp[a]) + base;

    float mx = sp[0];
    #pragma unroll
    for (int a = 1; a < A_SZ; ++a) mx = fmaxf(mx, sp[a]);
    float s = 0.0f;
    #pragma unroll
    for (int a = 0; a < A_SZ; ++a) { sp[a] = __expf(sp[a] - mx); s += sp[a]; }
    const float inv = 1.0f / s;

    float m0 = 0.0f, m1 = 0.0f;
    #pragma unroll
    for (int a = 0; a < A_SZ; ++a) { m0 += sp[a] * xv[a].x; m1 += sp[a] * xv[a].y; }
    m0 *= inv; m1 *= inv;

    ushort4v hb;
    hb.x = f2bf(hv.x); hb.y = f2bf(hv.y); hb.z = f2bf(hv.z); hb.w = f2bf(hv.w);
    *(ushort4v*)(Hb + (size_t)row * H_SZ + 4 * lane) = hb;
    ushort2v x1b; x1b.x = f2bf(x1v.x); x1b.y = f2bf(x1v.y);
    *(ushort2v*)(A1x + (size_t)row * E_SZ + 2 * lane) = x1b;
    ushort2v mb; mb.x = f2bf(m0); mb.y = f2bf(m1);
    *(ushort2v*)(A2x + (size_t)row * E_SZ + 2 * lane) = mb;
}

// ---------------- Kernel 2: weight pack: Wt[nn][k], nn = hcb*256 + g*32 + hc -
__global__ __launch_bounds__(256) void pack_w(Ptr8 ws, unsigned short* __restrict__ Wt)
{
    const int g = blockIdx.z, nt = blockIdx.y, kt = blockIdx.x;
    __shared__ float tile[64][65];
    const float* W = ws.p[g];
    const int c = threadIdx.x & 63, r0 = threadIdx.x >> 6;
    #pragma unroll
    for (int i = 0; i < 16; ++i) {
        int r = r0 + 4 * i;
        tile[r][c] = W[(size_t)(kt * 64 + r) * H_SZ + nt * 64 + c];
    }
    __syncthreads();
    #pragma unroll
    for (int i = 0; i < 16; ++i) {
        int rr = r0 + 4 * i;
        const int hcol = nt * 64 + rr;
        const int nn = ((hcol >> 5) << 8) + g * 32 + (hcol & 31);
        Wt[(size_t)nn * K_SZ + kt * 64 + c] = f2bf(tile[c][rr]);
    }
}

// ---------------- Kernel 3: barrier-free-K GEMM + fused LSTM epilogue -------
// Grid 2048 x 256thr (4 waves). Block = 64 rows x 256 gcols (8 gates x 32 hc).
// Wave w owns ALL 64 rows x gates {2w, 2w+1} (acc[4][4]). A staged ONCE into
// LDS (64KB swizzled, one barrier); B frags stream L2->reg with depth-2
// prefetch; NO barriers in the K loop -> waves free-run, memory flows.
__global__ __launch_bounds__(256) void gemm_ep(
    const unsigned short* __restrict__ Hb, const unsigned short* __restrict__ A1x,
    const unsigned short* __restrict__ A2x, const unsigned short* __restrict__ Wt,
    Ptr8 bias, const float* __restrict__ c1, const float* __restrict__ c2,
    float* __restrict__ out)
{
    __shared__ char smem[65536];  // A_h [64][512B swz] @0 | A_x [2][64][256B swz] @32K
    const int tid = threadIdx.x, w = tid >> 6, lane = tid & 63;
    const int d = blockIdx.x;
    // XCD-aware (2048 = 8*256, bijective): XCD owns 32 contiguous row-panels.
    const int lid = (d & 7) * 256 + (d >> 3);
    const int rb = lid >> 3, hcb = lid & 7;
    const int row0 = rb * 64, hcol0 = hcb * 32;
    const int fr = lane & 15, hi = lane >> 4;

    // ---- stage A once: h panel (32KB) + x panels (2x16KB) ----
    #pragma unroll
    for (int i = 0; i < 8; ++i) {                 // A_h
        const int o = i * 4096 + tid * 16;
        const int R = o >> 9, s = (o >> 4) & 31;
        const unsigned short* src = Hb + (size_t)(row0 + R) * H_SZ + ((s ^ (R & 7)) << 3);
        __builtin_amdgcn_global_load_lds(
            (const __attribute__((address_space(1))) unsigned int*)src,
            (__attribute__((address_space(3))) unsigned int*)(smem + i * 4096 + w * 1024),
            16, 0, 0);
    }
    #pragma unroll
    for (int i = 0; i < 8; ++i) {                 // A_x (i<4: cell1, i>=4: cell2)
        const int o = i * 4096 + tid * 16;
        const int R = (o >> 8) & 63, s = (o >> 4) & 15;
        const unsigned short* base = (i < 4) ? A1x : A2x;
        const unsigned short* src = base + (size_t)(row0 + R) * E_SZ + ((s ^ (R & 7)) << 3);
        __builtin_amdgcn_global_load_lds(
            (const __attribute__((address_space(1))) unsigned int*)src,
            (__attribute__((address_space(3))) unsigned int*)(smem + 32768 + i * 4096 + w * 1024),
            16, 0, 0);
    }

    const unsigned short* Wg = Wt + (size_t)hcb * 256 * K_SZ;
    const unsigned short* bb = Wg + (size_t)(w * 64 + fr) * K_SZ + hi * 8;
    const int xcell = w >> 1;                     // waves 0,1 -> cell1; 2,3 -> cell2

    f32x4 acc[4][4];
    #pragma unroll
    for (int mi = 0; mi < 4; ++mi)
        #pragma unroll
        for (int ni = 0; ni < 4; ++ni) acc[mi][ni] = (f32x4){0.f, 0.f, 0.f, 0.f};

    short8v af[2][4], bf[2][4];
    // B loads for kk=0 fly during the staging drain below
    #pragma unroll
    for (int ni = 0; ni < 4; ++ni)
        bf[0][ni] = *(const short8v*)(bb + (size_t)ni * 16 * K_SZ);

    __syncthreads();   // A staged (single drain for the whole kernel)

    #pragma unroll
    for (int mi = 0; mi < 4; ++mi) {
        const int R = mi * 16 + fr;
        af[0][mi] = *(const short8v*)(smem + R * 512 + ((hi ^ (R & 7)) << 4));
    }

    #pragma unroll
    for (int kk = 0; kk < 12; ++kk) {
        if (kk < 11) {
            const int kn = kk + 1;
            #pragma unroll
            for (int ni = 0; ni < 4; ++ni)
                bf[(kk + 1) & 1][ni] = *(const short8v*)(bb + (size_t)ni * 16 * K_SZ + kn * 32);
            if (kn < 8) {
                #pragma unroll
                for (int mi = 0; mi < 4; ++mi) {
                    const int R = mi * 16 + fr;
                    af[(kk + 1) & 1][mi] = *(const short8v*)(
                        smem + R * 512 + ((((kn << 2) + hi) ^ (R & 7)) << 4));
                }
            } else {
                #pragma unroll
                for (int mi = 0; mi < 4; ++mi) {
                    const int R = mi * 16 + fr;
                    af[(kk + 1) & 1][mi] = *(const short8v*)(
                        smem + 32768 + xcell * 16384 + R * 256 +
                        (((((kn - 8) << 2) + hi) ^ (R & 7)) << 4));
                }
            }
        }
        #pragma unroll
        for (int mi = 0; mi < 4; ++mi)
            #pragma unroll
            for (int ni = 0; ni < 4; ++ni)
                acc[mi][ni] = __builtin_amdgcn_mfma_f32_16x16x32_bf16(
                    af[kk & 1][mi], bf[kk & 1][ni], acc[mi][ni], 0, 0, 0);
    }

    // ---- epilogue: c/bias loads issued first (hide under exchange) ----
    const int hcin = tid & 31, rgrp = tid >> 5;   // rgrp 0..7
    float c1p[8], c2p[8], bia[8];
    #pragma unroll
    for (int rr = 0; rr < 8; ++rr) {
        const int R = rr * 8 + rgrp;
        c1p[rr] = c1[(size_t)(row0 + R) * H_SZ + hcol0 + hcin];
        c2p[rr] = c2[(size_t)(row0 + R) * H_SZ + hcol0 + hcin];
    }
    #pragma unroll
    for (int g = 0; g < 8; ++g) bia[g] = bias.p[g][hcol0 + hcin];

    __syncthreads();                              // K-loop LDS reads complete
    float* gf = (float*)smem;                     // [8 g][64 r][32 hc] = 64KB
    #pragma unroll
    for (int mi = 0; mi < 4; ++mi)
        #pragma unroll
        for (int ni = 0; ni < 4; ++ni)
            #pragma unroll
            for (int j = 0; j < 4; ++j) {
                const int R  = mi * 16 + hi * 4 + j;
                const int g  = w * 2 + (ni >> 1);
                const int hc = (ni & 1) * 16 + fr;
                gf[(g * 64 + R) * 32 + hc] = acc[mi][ni][j];
            }
    __syncthreads();

    #pragma unroll
    for (int rr = 0; rr < 8; ++rr) {
        const int R = rr * 8 + rgrp;
        float G[8];
        #pragma unroll
        for (int g = 0; g < 8; ++g) G[g] = gf[(g * 64 + R) * 32 + hcin] + bia[g];

        const float f1  = sigm(G[0]);
        const float i1  = sigm(G[1]);
        const float c1t = tanhf(G[2]);
        const float o1  = G[3];
        const float f2  = sigm(G[4]);
        const float i2  = sigm(G[5]);
        const float c2t = tanhf(G[6]);
        const float o2  = G[7];
        const float c1n = f1 * c1p[rr] + i1 * c1t;
        const float c2n = f2 * c2p[rr] + i2 * c2t;
        const float mo  = fmaxf(o1, o2);
        const float e1  = __expf(o1 - mo), e2 = __expf(o2 - mo);
        const float g0  = e1 / (e1 + e2);
        const float hn  = g0 * tanhf(c1n) + (1.0f - g0) * tanhf(c2n);

        const size_t o0 = (size_t)(row0 + R) * H_SZ + hcol0 + hcin;
        out[o0]          = hn;
        out[BH + o0]     = c1n;
        out[2 * BH + o0] = c2n;
    }
}

// ---------------- host ----------------
extern "C" void kernel_launch(void* const* d_in, const int* in_sizes, int n_in,
                              void* d_out, int out_size, void* d_ws, size_t ws_size,
                              hipStream_t stream)
{
    const float* x1 = (const float*)d_in[0];
    const float* x2 = (const float*)d_in[1];
    const float* h  = (const float*)d_in[2];
    const float* c1 = (const float*)d_in[3];
    const float* c2 = (const float*)d_in[4];
    const float* wa = (const float*)d_in[21];

    // gate order: 0..3 = cell1 {f,i,c,o}; 4..7 = cell2 {f,i,c,o}
    Ptr8 wptr, bptr;
    wptr.p[0] = (const float*)d_in[5];  wptr.p[1] = (const float*)d_in[9];
    wptr.p[2] = (const float*)d_in[13]; wptr.p[3] = (const float*)d_in[17];
    wptr.p[4] = (const float*)d_in[6];  wptr.p[5] = (const float*)d_in[10];
    wptr.p[6] = (const float*)d_in[14]; wptr.p[7] = (const float*)d_in[18];
    bptr.p[0] = (const float*)d_in[7];  bptr.p[1] = (const float*)d_in[11];
    bptr.p[2] = (const float*)d_in[15]; bptr.p[3] = (const float*)d_in[19];
    bptr.p[4] = (const float*)d_in[8];  bptr.p[5] = (const float*)d_in[12];
    bptr.p[6] = (const float*)d_in[16]; bptr.p[7] = (const float*)d_in[20];

    char* ws = (char*)d_ws;
    unsigned short* Hb  = (unsigned short*)(ws);              // 8.4 MB
    unsigned short* A1x = (unsigned short*)(ws + 8388608);    // 4.2 MB
    unsigned short* A2x = (unsigned short*)(ws + 12582912);   // 4.2 MB
    unsigned short* Wt  = (unsigned short*)(ws + 16777216);   // 1.6 MB

    pack_w<<<dim3(6, 4, 8), 256, 0, stream>>>(wptr, Wt);
    attn_pack<<<B_SZ / 4, 256, 0, stream>>>(x1, x2, h, wa, Hb, A1x, A2x);
    gemm_ep<<<2048, 256, 0, stream>>>(Hb, A1x, A2x, Wt, bptr, c1, c2, (float*)d_out);
}

// Round 8
// 112.742 us; speedup vs baseline: 1.1133x; 1.0168x over previous
//
#include <hip/hip_runtime.h>
#include <hip/hip_bf16.h>

#define B_SZ 16384
#define E_SZ 128
#define H_SZ 256
#define A_SZ 20
#define K_SZ 384           // H + E
#define BH   (B_SZ * H_SZ) // 4194304

typedef __attribute__((ext_vector_type(8))) short  short8v;
typedef __attribute__((ext_vector_type(4))) float  f32x4;
typedef __attribute__((ext_vector_type(2))) float  f32x2;
typedef __attribute__((ext_vector_type(4))) unsigned short ushort4v;
typedef __attribute__((ext_vector_type(2))) unsigned short ushort2v;

__device__ __forceinline__ unsigned short f2bf(float f) {
    union { float f; unsigned u; } v; v.f = f;
    unsigned r = v.u + 0x7fffu + ((v.u >> 16) & 1u);   // RNE
    return (unsigned short)(r >> 16);
}

__device__ __forceinline__ float wsum(float v) {
    #pragma unroll
    for (int off = 32; off > 0; off >>= 1) v += __shfl_xor(v, off, 64);
    return v;
}

__device__ __forceinline__ float sigm(float x) { return 1.0f / (1.0f + __expf(-x)); }

struct Ptr8 { const float* p[8]; };

// ---------------- Kernel 1: attention + bf16 pack: Hb=[h], A1x=[x1], A2x=[x2m]
__global__ __launch_bounds__(256) void attn_pack(
    const float* __restrict__ x1, const float* __restrict__ x2,
    const float* __restrict__ h,  const float* __restrict__ wa,
    unsigned short* __restrict__ Hb, unsigned short* __restrict__ A1x,
    unsigned short* __restrict__ A2x)
{
    const int row  = blockIdx.x * 4 + (threadIdx.x >> 6);
    const int lane = threadIdx.x & 63;

    const f32x4 hv   = *(const f32x4*)(h  + (size_t)row * H_SZ + 4 * lane);
    const f32x2 x1v  = *(const f32x2*)(x1 + (size_t)row * E_SZ + 2 * lane);
    const f32x4 wah  = *(const f32x4*)(wa + 4 * lane);
    const f32x2 wax1 = *(const f32x2*)(wa + H_SZ + 2 * lane);
    const f32x2 wax2 = *(const f32x2*)(wa + H_SZ + E_SZ + 2 * lane);

    float base = hv.x * wah.x + hv.y * wah.y + hv.z * wah.z + hv.w * wah.w
               + x1v.x * wax1.x + x1v.y * wax1.y;

    f32x2 xv[A_SZ];
    float sp[A_SZ];
    const float* x2r = x2 + (size_t)row * A_SZ * E_SZ;
    #pragma unroll
    for (int a = 0; a < A_SZ; ++a) {
        xv[a] = *(const f32x2*)(x2r + a * E_SZ + 2 * lane);
        sp[a] = xv[a].x * wax2.x + xv[a].y * wax2.y;
    }

    base = wsum(base);
    #pragma unroll
    for (int a = 0; a < A_SZ; ++a) sp[a] = wsum(sp[a]) + base;

    float mx = sp[0];
    #pragma unroll
    for (int a = 1; a < A_SZ; ++a) mx = fmaxf(mx, sp[a]);
    float s = 0.0f;
    #pragma unroll
    for (int a = 0; a < A_SZ; ++a) { sp[a] = __expf(sp[a] - mx); s += sp[a]; }
    const float inv = 1.0f / s;

    float m0 = 0.0f, m1 = 0.0f;
    #pragma unroll
    for (int a = 0; a < A_SZ; ++a) { m0 += sp[a] * xv[a].x; m1 += sp[a] * xv[a].y; }
    m0 *= inv; m1 *= inv;

    ushort4v hb;
    hb.x = f2bf(hv.x); hb.y = f2bf(hv.y); hb.z = f2bf(hv.z); hb.w = f2bf(hv.w);
    *(ushort4v*)(Hb + (size_t)row * H_SZ + 4 * lane) = hb;
    ushort2v x1b; x1b.x = f2bf(x1v.x); x1b.y = f2bf(x1v.y);
    *(ushort2v*)(A1x + (size_t)row * E_SZ + 2 * lane) = x1b;
    ushort2v mb; mb.x = f2bf(m0); mb.y = f2bf(m1);
    *(ushort2v*)(A2x + (size_t)row * E_SZ + 2 * lane) = mb;
}

// ---------------- Kernel 2: weight pack: Wt[nn][k], nn = hcb*256 + g*32 + hc -
__global__ __launch_bounds__(256) void pack_w(Ptr8 ws, unsigned short* __restrict__ Wt)
{
    const int g = blockIdx.z, nt = blockIdx.y, kt = blockIdx.x;
    __shared__ float tile[64][65];
    const float* W = ws.p[g];
    const int c = threadIdx.x & 63, r0 = threadIdx.x >> 6;
    #pragma unroll
    for (int i = 0; i < 16; ++i) {
        int r = r0 + 4 * i;
        tile[r][c] = W[(size_t)(kt * 64 + r) * H_SZ + nt * 64 + c];
    }
    __syncthreads();
    #pragma unroll
    for (int i = 0; i < 16; ++i) {
        int rr = r0 + 4 * i;
        const int hcol = nt * 64 + rr;
        const int nn = ((hcol >> 5) << 8) + g * 32 + (hcol & 31);
        Wt[(size_t)nn * K_SZ + kt * 64 + c] = f2bf(tile[c][rr]);
    }
}

#define WAITV(N) asm volatile("s_waitcnt vmcnt(" #N ")" ::: "memory")

// ---------------- Kernel 3: dbuf + counted-vmcnt GEMM + fused LSTM epilogue -
// Grid 1024 x 512thr. Block = 128 rows x 256 gcols (8 gates x 32 hc), 8 waves
// 2Mx4N, wave 64x64 acc[4][4]. BK=64, 6 K-steps, DOUBLE-buffered 128KB LDS.
// T3/T4: stage(t+1) issued at iter top; s_waitcnt vmcnt(N) counted so stage
// loads stay in flight ACROSS barriers (never drains the fresh stage).
__global__ __launch_bounds__(512, 1) void gemm_ep(
    const unsigned short* __restrict__ Hb, const unsigned short* __restrict__ A1x,
    const unsigned short* __restrict__ A2x, const unsigned short* __restrict__ Wt,
    Ptr8 bias, const float* __restrict__ c1, const float* __restrict__ c2,
    float* __restrict__ out)
{
    __shared__ char smem[131072];   // 2 x [A 32K | B 32K]; buf0 reused as epilogue gf
    const int tid = threadIdx.x, w = tid >> 6, lane = tid & 63;
    const int d = blockIdx.x;
    // XCD-aware (bijective for 1024): XCD owns 16 contiguous rbs x all 8 hcb.
    const int rb  = (d & 7) * 16 + (d >> 6);
    const int hcb = (d >> 3) & 7;
    const int row0 = rb * 128, hcol0 = hcb * 32;
    const int fr = lane & 15, hi = lane >> 4;
    const int wM = w >> 2, wN = w & 3;

    const unsigned short* Bpan = Wt + (size_t)hcb * 256 * K_SZ;

    // ---- epilogue operand prefetch (oldest loads; drain at first WAITV) ----
    const int hcin = tid & 31, rgrp = tid >> 5;     // rgrp 0..15
    float c1p[2][4], c2p[2][4], bia[8];
    #pragma unroll
    for (int p = 0; p < 2; ++p)
        #pragma unroll
        for (int rr = 0; rr < 4; ++rr) {
            const int R = p * 64 + rgrp * 4 + rr;
            c1p[p][rr] = c1[(size_t)(row0 + R) * H_SZ + hcol0 + hcin];
            c2p[p][rr] = c2[(size_t)(row0 + R) * H_SZ + hcol0 + hcin];
        }
    #pragma unroll
    for (int g = 0; g < 8; ++g) bia[g] = bias.p[g][hcol0 + hcin];

    auto glds = [&](const unsigned short* src, int dstoff) {
        __builtin_amdgcn_global_load_lds(
            (const __attribute__((address_space(1))) unsigned int*)src,
            (__attribute__((address_space(3))) unsigned int*)(smem + dstoff), 16, 0, 0);
    };
    // stage step t into buffer b. t<4: h-phase (6 loads/thr), t>=4: x (8/thr).
    auto stage = [&](int t, int b) {
        const int bufb = b * 65536;
        #pragma unroll
        for (int j = 0; j < 4; ++j) {            // B: 256 cols x 64k = 32KB
            const int o = j * 8192 + tid * 16;
            const int C = o >> 7, sl = (o >> 4) & 7;
            glds(Bpan + (size_t)C * K_SZ + t * 64 + ((sl ^ (C & 7)) << 3),
                 bufb + 32768 + j * 8192 + w * 1024);
        }
        if (t < 4) {                             // shared h panel: 128 x 64k = 16KB
            #pragma unroll
            for (int i = 0; i < 2; ++i) {
                const int o = i * 8192 + tid * 16;
                const int R = o >> 7, sl = (o >> 4) & 7;
                glds(Hb + (size_t)(row0 + R) * H_SZ + t * 64 + ((sl ^ (R & 7)) << 3),
                     bufb + i * 8192 + w * 1024);
            }
        } else {                                 // split x panels: 2 x 16KB
            const int ko = (t - 4) * 64;
            #pragma unroll
            for (int i = 0; i < 2; ++i) {
                const int o = i * 8192 + tid * 16;
                const int R = o >> 7, sl = (o >> 4) & 7;
                const int sw = (sl ^ (R & 7)) << 3;
                glds(A1x + (size_t)(row0 + R) * E_SZ + ko + sw,
                     bufb + i * 8192 + w * 1024);
                glds(A2x + (size_t)(row0 + R) * E_SZ + ko + sw,
                     bufb + 16384 + i * 8192 + w * 1024);
            }
        }
    };

    f32x4 acc[4][4];
    #pragma unroll
    for (int mi = 0; mi < 4; ++mi)
        #pragma unroll
        for (int ni = 0; ni < 4; ++ni) acc[mi][ni] = (f32x4){0.f, 0.f, 0.f, 0.f};

    stage(0, 0);

    #pragma unroll
    for (int t = 0; t < 6; ++t) {
        if (t < 5) stage(t + 1, (t + 1) & 1);
        // counted wait: drains exactly stage(t) (+ older), keeps stage(t+1) flying
        if (t == 0 || t == 1 || t == 2) { WAITV(6); }
        else if (t == 3 || t == 4)      { WAITV(8); }
        else                            { WAITV(0); }
        __builtin_amdgcn_s_barrier();            // all waves' stage(t) landed

        const char* bb = smem + (t & 1) * 65536;
        const int apo = (t >= 4 && wN >= 2) ? 16384 : 0;
        __builtin_amdgcn_s_setprio(1);
        #pragma unroll
        for (int kk = 0; kk < 2; ++kk) {
            short8v af[4], bf[4];
            #pragma unroll
            for (int mi = 0; mi < 4; ++mi) {
                const int R = wM * 64 + mi * 16 + fr;
                af[mi] = *(const short8v*)(bb + apo + R * 128 +
                                           ((((kk << 2) + hi) ^ (R & 7)) << 4));
            }
            #pragma unroll
            for (int ni = 0; ni < 4; ++ni) {
                const int C = wN * 64 + ni * 16 + fr;
                bf[ni] = *(const short8v*)(bb + 32768 + C * 128 +
                                           ((((kk << 2) + hi) ^ (C & 7)) << 4));
            }
            #pragma unroll
            for (int mi = 0; mi < 4; ++mi)
                #pragma unroll
                for (int ni = 0; ni < 4; ++ni)
                    acc[mi][ni] = __builtin_amdgcn_mfma_f32_16x16x32_bf16(
                        af[mi], bf[ni], acc[mi][ni], 0, 0, 0);
        }
        __builtin_amdgcn_s_setprio(0);
        __builtin_amdgcn_s_barrier();            // reads of buf[t&1] complete
    }

    // ---- epilogue: two 64-row phases through buf0 (64KB) ----
    float* gf = (float*)smem;                    // [8 g][64 r][32 hc], parity-rot
    #pragma unroll
    for (int p = 0; p < 2; ++p) {
        __syncthreads();
        if (wM == p) {
            #pragma unroll
            for (int mi = 0; mi < 4; ++mi)
                #pragma unroll
                for (int ni = 0; ni < 4; ++ni)
                    #pragma unroll
                    for (int j = 0; j < 4; ++j) {
                        const int Rl2 = mi * 16 + hi * 4 + j;          // 0..63
                        const int g   = wN * 2 + (ni >> 1);
                        const int hc  = (ni & 1) * 16 + fr;
                        const int hcr = (hc + (((Rl2 >> 2) & 1) << 4)) & 31;
                        gf[(g * 64 + Rl2) * 32 + hcr] = acc[mi][ni][j];
                    }
        }
        __syncthreads();
        #pragma unroll
        for (int rr = 0; rr < 4; ++rr) {
            const int Rl2 = rgrp * 4 + rr;
            const int hcr = (hcin + (((Rl2 >> 2) & 1) << 4)) & 31;
            float G[8];
            #pragma unroll
            for (int g = 0; g < 8; ++g) G[g] = gf[(g * 64 + Rl2) * 32 + hcr] + bia[g];

            const float f1  = sigm(G[0]);
            const float i1  = sigm(G[1]);
            const float c1t = tanhf(G[2]);
            const float o1  = G[3];
            const float f2  = sigm(G[4]);
            const float i2  = sigm(G[5]);
            const float c2t = tanhf(G[6]);
            const float o2  = G[7];
            const float c1n = f1 * c1p[p][rr] + i1 * c1t;
            const float c2n = f2 * c2p[p][rr] + i2 * c2t;
            const float mo  = fmaxf(o1, o2);
            const float e1  = __expf(o1 - mo), e2 = __expf(o2 - mo);
            const float g0  = e1 / (e1 + e2);
            const float hn  = g0 * tanhf(c1n) + (1.0f - g0) * tanhf(c2n);

            const size_t o0 = (size_t)(row0 + p * 64 + Rl2) * H_SZ + hcol0 + hcin;
            out[o0]          = hn;
            out[BH + o0]     = c1n;
            out[2 * BH + o0] = c2n;
        }
    }
}

// ---------------- host ----------------
extern "C" void kernel_launch(void* const* d_in, const int* in_sizes, int n_in,
                              void* d_out, int out_size, void* d_ws, size_t ws_size,
                              hipStream_t stream)
{
    const float* x1 = (const float*)d_in[0];
    const float* x2 = (const float*)d_in[1];
    const float* h  = (const float*)d_in[2];
    const float* c1 = (const float*)d_in[3];
    const float* c2 = (const float*)d_in[4];
    const float* wa = (const float*)d_in[21];

    // gate order: 0..3 = cell1 {f,i,c,o}; 4..7 = cell2 {f,i,c,o}
    Ptr8 wptr, bptr;
    wptr.p[0] = (const float*)d_in[5];  wptr.p[1] = (const float*)d_in[9];
    wptr.p[2] = (const float*)d_in[13]; wptr.p[3] = (const float*)d_in[17];
    wptr.p[4] = (const float*)d_in[6];  wptr.p[5] = (const float*)d_in[10];
    wptr.p[6] = (const float*)d_in[14]; wptr.p[7] = (const float*)d_in[18];
    bptr.p[0] = (const float*)d_in[7];  bptr.p[1] = (const float*)d_in[11];
    bptr.p[2] = (const float*)d_in[15]; bptr.p[3] = (const float*)d_in[19];
    bptr.p[4] = (const float*)d_in[8];  bptr.p[5] = (const float*)d_in[12];
    bptr.p[6] = (const float*)d_in[16]; bptr.p[7] = (const float*)d_in[20];

    char* ws = (char*)d_ws;
    unsigned short* Hb  = (unsigned short*)(ws);              // 8.4 MB
    unsigned short* A1x = (unsigned short*)(ws + 8388608);    // 4.2 MB
    unsigned short* A2x = (unsigned short*)(ws + 12582912);   // 4.2 MB
    unsigned short* Wt  = (unsigned short*)(ws + 16777216);   // 1.6 MB

    pack_w<<<dim3(6, 4, 8), 256, 0, stream>>>(wptr, Wt);
    attn_pack<<<B_SZ / 4, 256, 0, stream>>>(x1, x2, h, wa, Hb, A1x, A2x);
    gemm_ep<<<1024, 512, 0, stream>>>(Hb, A1x, A2x, Wt, bptr, c1, c2, (float*)d_out);
}

// Round 9
// 111.968 us; speedup vs baseline: 1.1210x; 1.0069x over previous
//
#include <hip/hip_runtime.h>
#include <hip/hip_bf16.h>

#define B_SZ 16384
#define E_SZ 128
#define H_SZ 256
#define A_SZ 20
#define K_SZ 384           // H + E
#define BH   (B_SZ * H_SZ) // 4194304

typedef __attribute__((ext_vector_type(8))) short  short8v;
typedef __attribute__((ext_vector_type(4))) float  f32x4;
typedef __attribute__((ext_vector_type(2))) float  f32x2;
typedef __attribute__((ext_vector_type(4))) unsigned short ushort4v;
typedef __attribute__((ext_vector_type(2))) unsigned short ushort2v;

__device__ __forceinline__ unsigned short f2bf(float f) {
    union { float f; unsigned u; } v; v.f = f;
    unsigned r = v.u + 0x7fffu + ((v.u >> 16) & 1u);   // RNE
    return (unsigned short)(r >> 16);
}

__device__ __forceinline__ float wsum(float v) {
    #pragma unroll
    for (int off = 32; off > 0; off >>= 1) v += __shfl_xor(v, off, 64);
    return v;
}

// fast epilogue math: v_exp (TRANS pipe) + v_rcp, ~6 instr vs ~50 for libm
__device__ __forceinline__ float tanh_fast(float x) {
    float cx = fminf(fmaxf(x, -15.f), 15.f);
    float t  = __expf(2.f * cx);                  // e^{2x} <= e^30, no inf
    return (t - 1.f) * __builtin_amdgcn_rcpf(t + 1.f);
}
__device__ __forceinline__ float sigm_fast(float x) {
    float cx = fminf(fmaxf(x, -30.f), 30.f);
    return __builtin_amdgcn_rcpf(1.f + __expf(-cx));
}

struct Ptr8 { const float* p[8]; };

// ---------------- Kernel 1: attention + bf16 pack: Hb=[h], A1x=[x1], A2x=[x2m]
__global__ __launch_bounds__(256) void attn_pack(
    const float* __restrict__ x1, const float* __restrict__ x2,
    const float* __restrict__ h,  const float* __restrict__ wa,
    unsigned short* __restrict__ Hb, unsigned short* __restrict__ A1x,
    unsigned short* __restrict__ A2x)
{
    const int row  = blockIdx.x * 4 + (threadIdx.x >> 6);
    const int lane = threadIdx.x & 63;

    const f32x4 hv   = *(const f32x4*)(h  + (size_t)row * H_SZ + 4 * lane);
    const f32x2 x1v  = *(const f32x2*)(x1 + (size_t)row * E_SZ + 2 * lane);
    const f32x4 wah  = *(const f32x4*)(wa + 4 * lane);
    const f32x2 wax1 = *(const f32x2*)(wa + H_SZ + 2 * lane);
    const f32x2 wax2 = *(const f32x2*)(wa + H_SZ + E_SZ + 2 * lane);

    float base = hv.x * wah.x + hv.y * wah.y + hv.z * wah.z + hv.w * wah.w
               + x1v.x * wax1.x + x1v.y * wax1.y;

    f32x2 xv[A_SZ];
    float sp[A_SZ];
    const float* x2r = x2 + (size_t)row * A_SZ * E_SZ;
    #pragma unroll
    for (int a = 0; a < A_SZ; ++a) {
        xv[a] = *(const f32x2*)(x2r + a * E_SZ + 2 * lane);
        sp[a] = xv[a].x * wax2.x + xv[a].y * wax2.y;
    }

    base = wsum(base);
    #pragma unroll
    for (int a = 0; a < A_SZ; ++a) sp[a] = wsum(sp[a]) + base;

    float mx = sp[0];
    #pragma unroll
    for (int a = 1; a < A_SZ; ++a) mx = fmaxf(mx, sp[a]);
    float s = 0.0f;
    #pragma unroll
    for (int a = 0; a < A_SZ; ++a) { sp[a] = __expf(sp[a] - mx); s += sp[a]; }
    const float inv = 1.0f / s;

    float m0 = 0.0f, m1 = 0.0f;
    #pragma unroll
    for (int a = 0; a < A_SZ; ++a) { m0 += sp[a] * xv[a].x; m1 += sp[a] * xv[a].y; }
    m0 *= inv; m1 *= inv;

    ushort4v hb;
    hb.x = f2bf(hv.x); hb.y = f2bf(hv.y); hb.z = f2bf(hv.z); hb.w = f2bf(hv.w);
    *(ushort4v*)(Hb + (size_t)row * H_SZ + 4 * lane) = hb;
    ushort2v x1b; x1b.x = f2bf(x1v.x); x1b.y = f2bf(x1v.y);
    *(ushort2v*)(A1x + (size_t)row * E_SZ + 2 * lane) = x1b;
    ushort2v mb; mb.x = f2bf(m0); mb.y = f2bf(m1);
    *(ushort2v*)(A2x + (size_t)row * E_SZ + 2 * lane) = mb;
}

// ---------------- Kernel 2: weight pack: Wt[nn][k], nn = hcb*256 + g*32 + hc -
__global__ __launch_bounds__(256) void pack_w(Ptr8 ws, unsigned short* __restrict__ Wt)
{
    const int g = blockIdx.z, nt = blockIdx.y, kt = blockIdx.x;
    __shared__ float tile[64][65];
    const float* W = ws.p[g];
    const int c = threadIdx.x & 63, r0 = threadIdx.x >> 6;
    #pragma unroll
    for (int i = 0; i < 16; ++i) {
        int r = r0 + 4 * i;
        tile[r][c] = W[(size_t)(kt * 64 + r) * H_SZ + nt * 64 + c];
    }
    __syncthreads();
    #pragma unroll
    for (int i = 0; i < 16; ++i) {
        int rr = r0 + 4 * i;
        const int hcol = nt * 64 + rr;
        const int nn = ((hcol >> 5) << 8) + g * 32 + (hcol & 31);
        Wt[(size_t)nn * K_SZ + kt * 64 + c] = f2bf(tile[c][rr]);
    }
}

// ---------------- Kernel 3: GEMM + fused LSTM epilogue (R5 structure) -------
// Grid 1024 x 512thr, 2 blocks/CU. Block = 128 rows x 256 cols (8g x 32hc).
// 8 waves 2Mx4N, wave tile 64x64. A shared for K<256 (h part), split after.
__global__ __launch_bounds__(512, 4) void gemm_ep(
    const unsigned short* __restrict__ Hb, const unsigned short* __restrict__ A1x,
    const unsigned short* __restrict__ A2x, const unsigned short* __restrict__ Wt,
    Ptr8 bias, const float* __restrict__ c1, const float* __restrict__ c2,
    float* __restrict__ out)
{
    __shared__ char smem[65536];   // A 0..32K (16K used for ks<4) | B 32K..64K
    const int tid = threadIdx.x, w = tid >> 6, lane = tid & 63;
    const int d = blockIdx.x;
    // XCD-aware (bijective for 1024 = 8*128): XCD owns 16 contiguous rbs.
    const int rb  = (d & 7) * 16 + (d >> 6);
    const int hcb = (d >> 3) & 7;
    const int row0 = rb * 128, hcol0 = hcb * 32;
    const int fr = lane & 15, hi = lane >> 4;
    const int wM = w >> 2, wN = w & 3;

    const unsigned short* Bpan = Wt + (size_t)hcb * 256 * K_SZ;
    const int lr = lane >> 3, sl = lane & 7;   // 8 rows x 8 16B-slots per glds

    // ---- prefetch ALL epilogue operands before K-loop (latency hidden) ----
    const int hcin = tid & 31, rgrp = tid >> 5;     // rgrp 0..15
    float c1p[2][4], c2p[2][4], bia[8];
    #pragma unroll
    for (int p = 0; p < 2; ++p)
        #pragma unroll
        for (int rr = 0; rr < 4; ++rr) {
            const int R = p * 64 + rgrp * 4 + rr;
            c1p[p][rr] = c1[(size_t)(row0 + R) * H_SZ + hcol0 + hcin];
            c2p[p][rr] = c2[(size_t)(row0 + R) * H_SZ + hcol0 + hcin];
        }
    #pragma unroll
    for (int g = 0; g < 8; ++g) bia[g] = bias.p[g][hcol0 + hcin];

    auto glds = [&](const unsigned short* src, int dstoff) {
        __builtin_amdgcn_global_load_lds(
            (const __attribute__((address_space(1))) unsigned int*)src,
            (__attribute__((address_space(3))) unsigned int*)(smem + dstoff), 16, 0, 0);
    };
    auto stage = [&](int ks) {
        #pragma unroll
        for (int j = 0; j < 4; ++j) {            // B panel: 256 cols x 64 k
            const int C = j * 64 + w * 8 + lr;
            glds(Bpan + (size_t)C * K_SZ + ks * 64 + ((sl ^ (C & 7)) << 3),
                 32768 + j * 8192 + w * 1024);
        }
        if (ks < 4) {                            // shared h panel
            #pragma unroll
            for (int i = 0; i < 2; ++i) {
                const int R = i * 64 + w * 8 + lr;
                glds(Hb + (size_t)(row0 + R) * H_SZ + ks * 64 + ((sl ^ (R & 7)) << 3),
                     i * 8192 + w * 1024);
            }
        } else {                                 // split x panels
            const int ko = (ks - 4) * 64;
            #pragma unroll
            for (int i = 0; i < 2; ++i) {
                const int R = i * 64 + w * 8 + lr;
                const int sw = (sl ^ (R & 7)) << 3;
                glds(A1x + (size_t)(row0 + R) * E_SZ + ko + sw,         i * 8192 + w * 1024);
                glds(A2x + (size_t)(row0 + R) * E_SZ + ko + sw, 16384 + i * 8192 + w * 1024);
            }
        }
    };

    f32x4 acc[4][4];
    #pragma unroll
    for (int mi = 0; mi < 4; ++mi)
        #pragma unroll
        for (int ni = 0; ni < 4; ++ni) acc[mi][ni] = (f32x4){0.f, 0.f, 0.f, 0.f};

    stage(0);
    for (int ks = 0; ks < 6; ++ks) {
        __syncthreads();                         // staging of ks complete
        const int apo = (ks >= 4 && wN >= 2) ? 16384 : 0;
        #pragma unroll
        for (int kk = 0; kk < 2; ++kk) {
            short8v af[4], bf[4];
            #pragma unroll
            for (int mi = 0; mi < 4; ++mi) {
                const int R = wM * 64 + mi * 16 + fr;
                af[mi] = *(const short8v*)(smem + apo + R * 128 +
                                           ((((kk << 2) + hi) ^ (R & 7)) << 4));
            }
            #pragma unroll
            for (int ni = 0; ni < 4; ++ni) {
                const int C = wN * 64 + ni * 16 + fr;
                bf[ni] = *(const short8v*)(smem + 32768 + C * 128 +
                                           ((((kk << 2) + hi) ^ (C & 7)) << 4));
            }
            #pragma unroll
            for (int mi = 0; mi < 4; ++mi)
                #pragma unroll
                for (int ni = 0; ni < 4; ++ni)
                    acc[mi][ni] = __builtin_amdgcn_mfma_f32_16x16x32_bf16(
                        af[mi], bf[ni], acc[mi][ni], 0, 0, 0);
        }
        __syncthreads();                         // all reads done
        if (ks < 5) stage(ks + 1);               // refill (other block overlaps)
    }

    // ---- epilogue: two 64-row phases through the 64KB buffer ----
    float* gf = (float*)smem;                    // [8 g][64 r][32 c], parity-rot
    #pragma unroll
    for (int p = 0; p < 2; ++p) {
        __syncthreads();
        if (wM == p) {
            #pragma unroll
            for (int mi = 0; mi < 4; ++mi)
                #pragma unroll
                for (int ni = 0; ni < 4; ++ni)
                    #pragma unroll
                    for (int j = 0; j < 4; ++j) {
                        const int Rl2 = mi * 16 + hi * 4 + j;          // 0..63
                        const int g   = wN * 2 + (ni >> 1);
                        const int hc  = (ni & 1) * 16 + fr;
                        const int hcr = (hc + (((Rl2 >> 2) & 1) << 4)) & 31;
                        gf[(g * 64 + Rl2) * 32 + hcr] = acc[mi][ni][j];
                    }
        }
        __syncthreads();
        #pragma unroll
        for (int rr = 0; rr < 4; ++rr) {
            const int Rl2 = rgrp * 4 + rr;
            const int hcr = (hcin + (((Rl2 >> 2) & 1) << 4)) & 31;
            float G[8];
            #pragma unroll
            for (int g = 0; g < 8; ++g) G[g] = gf[(g * 64 + Rl2) * 32 + hcr] + bia[g];

            const float f1  = sigm_fast(G[0]);
            const float i1  = sigm_fast(G[1]);
            const float c1t = tanh_fast(G[2]);
            const float f2  = sigm_fast(G[4]);
            const float i2  = sigm_fast(G[5]);
            const float c2t = tanh_fast(G[6]);
            const float c1n = f1 * c1p[p][rr] + i1 * c1t;
            const float c2n = f2 * c2p[p][rr] + i2 * c2t;
            const float g0  = sigm_fast(G[3] - G[7]);    // e1/(e1+e2)
            const float th1 = tanh_fast(c1n);
            const float th2 = tanh_fast(c2n);
            const float hn  = th2 + g0 * (th1 - th2);

            const size_t o0 = (size_t)(row0 + p * 64 + Rl2) * H_SZ + hcol0 + hcin;
            out[o0]          = hn;
            out[BH + o0]     = c1n;
            out[2 * BH + o0] = c2n;
        }
    }
}

// ---------------- host ----------------
extern "C" void kernel_launch(void* const* d_in, const int* in_sizes, int n_in,
                              void* d_out, int out_size, void* d_ws, size_t ws_size,
                              hipStream_t stream)
{
    const float* x1 = (const float*)d_in[0];
    const float* x2 = (const float*)d_in[1];
    const float* h  = (const float*)d_in[2];
    const float* c1 = (const float*)d_in[3];
    const float* c2 = (const float*)d_in[4];
    const float* wa = (const float*)d_in[21];

    // gate order: 0..3 = cell1 {f,i,c,o}; 4..7 = cell2 {f,i,c,o}
    Ptr8 wptr, bptr;
    wptr.p[0] = (const float*)d_in[5];  wptr.p[1] = (const float*)d_in[9];
    wptr.p[2] = (const float*)d_in[13]; wptr.p[3] = (const float*)d_in[17];
    wptr.p[4] = (const float*)d_in[6];  wptr.p[5] = (const float*)d_in[10];
    wptr.p[6] = (const float*)d_in[14]; wptr.p[7] = (const float*)d_in[18];
    bptr.p[0] = (const float*)d_in[7];  bptr.p[1] = (const float*)d_in[11];
    bptr.p[2] = (const float*)d_in[15]; bptr.p[3] = (const float*)d_in[19];
    bptr.p[4] = (const float*)d_in[8];  bptr.p[5] = (const float*)d_in[12];
    bptr.p[6] = (const float*)d_in[16]; bptr.p[7] = (const float*)d_in[20];

    char* ws = (char*)d_ws;
    unsigned short* Hb  = (unsigned short*)(ws);              // 8.4 MB
    unsigned short* A1x = (unsigned short*)(ws + 8388608);    // 4.2 MB
    unsigned short* A2x = (unsigned short*)(ws + 12582912);   // 4.2 MB
    unsigned short* Wt  = (unsigned short*)(ws + 16777216);   // 1.6 MB

    pack_w<<<dim3(6, 4, 8), 256, 0, stream>>>(wptr, Wt);
    attn_pack<<<B_SZ / 4, 256, 0, stream>>>(x1, x2, h, wa, Hb, A1x, A2x);
    gemm_ep<<<1024, 512, 0, stream>>>(Hb, A1x, A2x, Wt, bptr, c1, c2, (float*)d_out);
}

// Round 10
// 97.283 us; speedup vs baseline: 1.2902x; 1.1510x over previous
//
#include <hip/hip_runtime.h>
#include <hip/hip_bf16.h>

#define B_SZ 16384
#define E_SZ 128
#define H_SZ 256
#define A_SZ 20
#define K_SZ 384           // H + E
#define BH   (B_SZ * H_SZ) // 4194304

typedef __attribute__((ext_vector_type(8))) short  short8v;
typedef __attribute__((ext_vector_type(4))) float  f32x4;
typedef __attribute__((ext_vector_type(2))) float  f32x2;
typedef __attribute__((ext_vector_type(4))) unsigned short ushort4v;
typedef __attribute__((ext_vector_type(2))) unsigned short ushort2v;

__device__ __forceinline__ unsigned short f2bf(float f) {
    union { float f; unsigned u; } v; v.f = f;
    unsigned r = v.u + 0x7fffu + ((v.u >> 16) & 1u);   // RNE
    return (unsigned short)(r >> 16);
}

__device__ __forceinline__ float wsum(float v) {
    #pragma unroll
    for (int off = 32; off > 0; off >>= 1) v += __shfl_xor(v, off, 64);
    return v;
}

// fast epilogue math: v_exp (TRANS pipe) + v_rcp, ~6 instr vs ~50 for libm
__device__ __forceinline__ float tanh_fast(float x) {
    float cx = fminf(fmaxf(x, -15.f), 15.f);
    float t  = __expf(2.f * cx);                  // e^{2x} <= e^30, no inf
    return (t - 1.f) * __builtin_amdgcn_rcpf(t + 1.f);
}
__device__ __forceinline__ float sigm_fast(float x) {
    float cx = fminf(fmaxf(x, -30.f), 30.f);
    return __builtin_amdgcn_rcpf(1.f + __expf(-cx));
}

struct Ptr8 { const float* p[8]; };

// ---------------- Kernel 1: attention + bf16 pack: Hb=[h], A1x=[x1], A2x=[x2m]
__global__ __launch_bounds__(256) void attn_pack(
    const float* __restrict__ x1, const float* __restrict__ x2,
    const float* __restrict__ h,  const float* __restrict__ wa,
    unsigned short* __restrict__ Hb, unsigned short* __restrict__ A1x,
    unsigned short* __restrict__ A2x)
{
    const int row  = blockIdx.x * 4 + (threadIdx.x >> 6);
    const int lane = threadIdx.x & 63;

    const f32x4 hv   = *(const f32x4*)(h  + (size_t)row * H_SZ + 4 * lane);
    const f32x2 x1v  = *(const f32x2*)(x1 + (size_t)row * E_SZ + 2 * lane);
    const f32x4 wah  = *(const f32x4*)(wa + 4 * lane);
    const f32x2 wax1 = *(const f32x2*)(wa + H_SZ + 2 * lane);
    const f32x2 wax2 = *(const f32x2*)(wa + H_SZ + E_SZ + 2 * lane);

    float base = hv.x * wah.x + hv.y * wah.y + hv.z * wah.z + hv.w * wah.w
               + x1v.x * wax1.x + x1v.y * wax1.y;

    f32x2 xv[A_SZ];
    float sp[A_SZ];
    const float* x2r = x2 + (size_t)row * A_SZ * E_SZ;
    #pragma unroll
    for (int a = 0; a < A_SZ; ++a) {
        xv[a] = *(const f32x2*)(x2r + a * E_SZ + 2 * lane);
        sp[a] = xv[a].x * wax2.x + xv[a].y * wax2.y;
    }

    base = wsum(base);
    #pragma unroll
    for (int a = 0; a < A_SZ; ++a) sp[a] = wsum(sp[a]) + base;

    float mx = sp[0];
    #pragma unroll
    for (int a = 1; a < A_SZ; ++a) mx = fmaxf(mx, sp[a]);
    float s = 0.0f;
    #pragma unroll
    for (int a = 0; a < A_SZ; ++a) { sp[a] = __expf(sp[a] - mx); s += sp[a]; }
    const float inv = 1.0f / s;

    float m0 = 0.0f, m1 = 0.0f;
    #pragma unroll
    for (int a = 0; a < A_SZ; ++a) { m0 += sp[a] * xv[a].x; m1 += sp[a] * xv[a].y; }
    m0 *= inv; m1 *= inv;

    ushort4v hb;
    hb.x = f2bf(hv.x); hb.y = f2bf(hv.y); hb.z = f2bf(hv.z); hb.w = f2bf(hv.w);
    *(ushort4v*)(Hb + (size_t)row * H_SZ + 4 * lane) = hb;
    ushort2v x1b; x1b.x = f2bf(x1v.x); x1b.y = f2bf(x1v.y);
    *(ushort2v*)(A1x + (size_t)row * E_SZ + 2 * lane) = x1b;
    ushort2v mb; mb.x = f2bf(m0); mb.y = f2bf(m1);
    *(ushort2v*)(A2x + (size_t)row * E_SZ + 2 * lane) = mb;
}

// ---------------- Kernel 2: weight pack: Wt[nn][k], nn = hcb*256 + g*32 + hc -
__global__ __launch_bounds__(256) void pack_w(Ptr8 ws, unsigned short* __restrict__ Wt)
{
    const int g = blockIdx.z, nt = blockIdx.y, kt = blockIdx.x;
    __shared__ float tile[64][65];
    const float* W = ws.p[g];
    const int c = threadIdx.x & 63, r0 = threadIdx.x >> 6;
    #pragma unroll
    for (int i = 0; i < 16; ++i) {
        int r = r0 + 4 * i;
        tile[r][c] = W[(size_t)(kt * 64 + r) * H_SZ + nt * 64 + c];
    }
    __syncthreads();
    #pragma unroll
    for (int i = 0; i < 16; ++i) {
        int rr = r0 + 4 * i;
        const int hcol = nt * 64 + rr;
        const int nn = ((hcol >> 5) << 8) + g * 32 + (hcol & 31);
        Wt[(size_t)nn * K_SZ + kt * 64 + c] = f2bf(tile[c][rr]);
    }
}

// ---------------- Kernel 3: dbuf GEMM (m97 loop) + fast fused LSTM epilogue -
// Grid 1024 x 512thr, 128KB LDS (1 blk/CU). Block = 128 rows x 256 gcols.
// 8 waves 2Mx4N, wave 64x64 acc[4][4]. BK=64, 6 steps, double-buffered:
// barrier -> stage(t+1) -> compute(t); next barrier drains. Shared-h A panel.
__global__ __launch_bounds__(512, 1) void gemm_ep(
    const unsigned short* __restrict__ Hb, const unsigned short* __restrict__ A1x,
    const unsigned short* __restrict__ A2x, const unsigned short* __restrict__ Wt,
    Ptr8 bias, const float* __restrict__ c1, const float* __restrict__ c2,
    float* __restrict__ out)
{
    __shared__ char smem[131072];   // 2 x [A 32K | B 32K]; whole 128K = epilogue gf
    const int tid = threadIdx.x, w = tid >> 6, lane = tid & 63;
    const int d = blockIdx.x;
    // XCD-aware (bijective for 1024 = 8*128): XCD owns 16 contiguous rbs.
    const int rb  = (d & 7) * 16 + (d >> 6);
    const int hcb = (d >> 3) & 7;
    const int row0 = rb * 128, hcol0 = hcb * 32;
    const int fr = lane & 15, hi = lane >> 4;
    const int wM = w >> 2, wN = w & 3;

    const unsigned short* Bpan = Wt + (size_t)hcb * 256 * K_SZ;
    const int lr = lane >> 3, sl = lane & 7;   // 8 rows x 8 16B-slots per glds

    // ---- prefetch ALL epilogue operands before K-loop (latency hidden) ----
    const int hcin = tid & 31, rgrp = tid >> 5;     // rgrp 0..15
    float c1p[8], c2p[8], bia[8];
    #pragma unroll
    for (int rr = 0; rr < 8; ++rr) {
        const int R = rgrp * 8 + rr;
        c1p[rr] = c1[(size_t)(row0 + R) * H_SZ + hcol0 + hcin];
        c2p[rr] = c2[(size_t)(row0 + R) * H_SZ + hcol0 + hcin];
    }
    #pragma unroll
    for (int g = 0; g < 8; ++g) bia[g] = bias.p[g][hcol0 + hcin];

    auto glds = [&](const unsigned short* src, int dstoff) {
        __builtin_amdgcn_global_load_lds(
            (const __attribute__((address_space(1))) unsigned int*)src,
            (__attribute__((address_space(3))) unsigned int*)(smem + dstoff), 16, 0, 0);
    };
    // stage K-step ks into buffer b (b*65536): A @0 (h shared / x split), B @32K
    auto stage = [&](int ks, int b) {
        const int bufb = b * 65536;
        #pragma unroll
        for (int j = 0; j < 4; ++j) {            // B panel: 256 cols x 64 k
            const int C = j * 64 + w * 8 + lr;
            glds(Bpan + (size_t)C * K_SZ + ks * 64 + ((sl ^ (C & 7)) << 3),
                 bufb + 32768 + j * 8192 + w * 1024);
        }
        if (ks < 4) {                            // shared h panel: 128 x 64k
            #pragma unroll
            for (int i = 0; i < 2; ++i) {
                const int R = i * 64 + w * 8 + lr;
                glds(Hb + (size_t)(row0 + R) * H_SZ + ks * 64 + ((sl ^ (R & 7)) << 3),
                     bufb + i * 8192 + w * 1024);
            }
        } else {                                 // split x panels
            const int ko = (ks - 4) * 64;
            #pragma unroll
            for (int i = 0; i < 2; ++i) {
                const int R = i * 64 + w * 8 + lr;
                const int sw = (sl ^ (R & 7)) << 3;
                glds(A1x + (size_t)(row0 + R) * E_SZ + ko + sw,
                     bufb + i * 8192 + w * 1024);
                glds(A2x + (size_t)(row0 + R) * E_SZ + ko + sw,
                     bufb + 16384 + i * 8192 + w * 1024);
            }
        }
    };

    f32x4 acc[4][4];
    #pragma unroll
    for (int mi = 0; mi < 4; ++mi)
        #pragma unroll
        for (int ni = 0; ni < 4; ++ni) acc[mi][ni] = (f32x4){0.f, 0.f, 0.f, 0.f};

    stage(0, 0);
    for (int ks = 0; ks < 6; ++ks) {
        __syncthreads();                         // drains stage(ks)
        if (ks < 5) stage(ks + 1, (ks + 1) & 1); // flies under compute below
        const char* bb = smem + (ks & 1) * 65536;
        const int apo = (ks >= 4 && wN >= 2) ? 16384 : 0;
        #pragma unroll
        for (int kk = 0; kk < 2; ++kk) {
            short8v af[4], bf[4];
            #pragma unroll
            for (int mi = 0; mi < 4; ++mi) {
                const int R = wM * 64 + mi * 16 + fr;
                af[mi] = *(const short8v*)(bb + apo + R * 128 +
                                           ((((kk << 2) + hi) ^ (R & 7)) << 4));
            }
            #pragma unroll
            for (int ni = 0; ni < 4; ++ni) {
                const int C = wN * 64 + ni * 16 + fr;
                bf[ni] = *(const short8v*)(bb + 32768 + C * 128 +
                                           ((((kk << 2) + hi) ^ (C & 7)) << 4));
            }
            #pragma unroll
            for (int mi = 0; mi < 4; ++mi)
                #pragma unroll
                for (int ni = 0; ni < 4; ++ni)
                    acc[mi][ni] = __builtin_amdgcn_mfma_f32_16x16x32_bf16(
                        af[mi], bf[ni], acc[mi][ni], 0, 0, 0);
        }
    }

    // ---- epilogue: single 128-row exchange through all 128KB ----
    __syncthreads();                             // K-loop LDS reads complete
    float* gf = (float*)smem;                    // [8 g][128 r][32 hc], rot-swz
    #pragma unroll
    for (int mi = 0; mi < 4; ++mi)
        #pragma unroll
        for (int ni = 0; ni < 4; ++ni)
            #pragma unroll
            for (int j = 0; j < 4; ++j) {
                const int R   = wM * 64 + mi * 16 + hi * 4 + j;
                const int g   = wN * 2 + (ni >> 1);
                const int hc  = (ni & 1) * 16 + fr;
                const int hcr = (hc + (((R >> 2) & 3) << 3)) & 31;
                gf[(g * 128 + R) * 32 + hcr] = acc[mi][ni][j];
            }
    __syncthreads();

    #pragma unroll
    for (int rr = 0; rr < 8; ++rr) {
        const int R   = rgrp * 8 + rr;
        const int hcr = (hcin + (((R >> 2) & 3) << 3)) & 31;
        float G[8];
        #pragma unroll
        for (int g = 0; g < 8; ++g) G[g] = gf[(g * 128 + R) * 32 + hcr] + bia[g];

        const float f1  = sigm_fast(G[0]);
        const float i1  = sigm_fast(G[1]);
        const float c1t = tanh_fast(G[2]);
        const float f2  = sigm_fast(G[4]);
        const float i2  = sigm_fast(G[5]);
        const float c2t = tanh_fast(G[6]);
        const float c1n = f1 * c1p[rr] + i1 * c1t;
        const float c2n = f2 * c2p[rr] + i2 * c2t;
        const float g0  = sigm_fast(G[3] - G[7]);    // e1/(e1+e2)
        const float th1 = tanh_fast(c1n);
        const float th2 = tanh_fast(c2n);
        const float hn  = th2 + g0 * (th1 - th2);

        const size_t o0 = (size_t)(row0 + R) * H_SZ + hcol0 + hcin;
        out[o0]          = hn;
        out[BH + o0]     = c1n;
        out[2 * BH + o0] = c2n;
    }
}

// ---------------- host ----------------
extern "C" void kernel_launch(void* const* d_in, const int* in_sizes, int n_in,
                              void* d_out, int out_size, void* d_ws, size_t ws_size,
                              hipStream_t stream)
{
    const float* x1 = (const float*)d_in[0];
    const float* x2 = (const float*)d_in[1];
    const float* h  = (const float*)d_in[2];
    const float* c1 = (const float*)d_in[3];
    const float* c2 = (const float*)d_in[4];
    const float* wa = (const float*)d_in[21];

    // gate order: 0..3 = cell1 {f,i,c,o}; 4..7 = cell2 {f,i,c,o}
    Ptr8 wptr, bptr;
    wptr.p[0] = (const float*)d_in[5];  wptr.p[1] = (const float*)d_in[9];
    wptr.p[2] = (const float*)d_in[13]; wptr.p[3] = (const float*)d_in[17];
    wptr.p[4] = (const float*)d_in[6];  wptr.p[5] = (const float*)d_in[10];
    wptr.p[6] = (const float*)d_in[14]; wptr.p[7] = (const float*)d_in[18];
    bptr.p[0] = (const float*)d_in[7];  bptr.p[1] = (const float*)d_in[11];
    bptr.p[2] = (const float*)d_in[15]; bptr.p[3] = (const float*)d_in[19];
    bptr.p[4] = (const float*)d_in[8];  bptr.p[5] = (const float*)d_in[12];
    bptr.p[6] = (const float*)d_in[16]; bptr.p[7] = (const float*)d_in[20];

    char* ws = (char*)d_ws;
    unsigned short* Hb  = (unsigned short*)(ws);              // 8.4 MB
    unsigned short* A1x = (unsigned short*)(ws + 8388608);    // 4.2 MB
    unsigned short* A2x = (unsigned short*)(ws + 12582912);   // 4.2 MB
    unsigned short* Wt  = (unsigned short*)(ws + 16777216);   // 1.6 MB

    pack_w<<<dim3(6, 4, 8), 256, 0, stream>>>(wptr, Wt);
    attn_pack<<<B_SZ / 4, 256, 0, stream>>>(x1, x2, h, wa, Hb, A1x, A2x);
    gemm_ep<<<1024, 512, 0, stream>>>(Hb, A1x, A2x, Wt, bptr, c1, c2, (float*)d_out);
}